// Round 5
// baseline (3107.831 us; speedup 1.0000x reference)
//
#include <hip/hip_runtime.h>
#include <math.h>

typedef _Float16 f16;
typedef f16 f16x8 __attribute__((ext_vector_type(8)));
typedef float f32x4 __attribute__((ext_vector_type(4)));

#define MFMA16(a, b, c) __builtin_amdgcn_mfma_f32_16x16x32_f16((a), (b), (c), 0, 0, 0)

// ---------------------------------------------------------------------------
// ws layout (bytes):
//  Wg_t  fp16 [512][448]  @ 0        (gates t: cols 0:300 Wih, 320:448 Whh, rows n=4u+g)
//  Wg_a  fp16 [256][160]  @ 458752   (cols 0:81 Wih, 96:160 Whh)
//  Wg_v  fp16 [256][448]  @ 540672   (cols 0:371 Wih, 384:448 Whh)
//  W_a1  fp16 [128][512]  @ 770048
//  W_a2  fp16 [512][128]  @ 901120
//  W_b1  fp16 [128][512]  @ 1032192
//  W_b2  fp16 [256][128]  @ 1163264
//  W_g1  fp16 [256][768]  @ 1228800  rows 0:128 g1_W1, 128:256 g2_W1
//  W_g2  fp16 [512][128]  @ 1622016  rows 0:256 g1_W2, 256:512 g2_W2
//  W_o1  fp16 [128][512]  @ 1753088
//  bg    f32  [1024]      @ 1884160  gate bias, interleaved n=4u+g
//  X16   fp16 [20*4096][800] @ 2097152  (optional: x_p in f16, padded segments)
// ---------------------------------------------------------------------------

struct PackArgs {
  const float *t_Wih, *t_Whh, *t_b, *a_Wih, *a_Whh, *a_b, *v_Wih, *v_Whh, *v_b;
  const float *aW1, *aW2, *bW1, *bW2, *g1W1, *g2W1, *g1W2, *g2W2, *oW1;
  f16 *Wg_t, *Wg_a, *Wg_v, *W_a1, *W_a2, *W_b1, *W_b2, *W_g1, *W_g2, *W_o1;
  float *bg;
};

__global__ __launch_bounds__(256) void pack_w(PackArgs p) {
  int idx = blockIdx.x * 256 + threadIdx.x;
  if (idx < 229376) {  // Wg_t [512][448]
    int n = idx / 448, k = idx % 448;
    int srow = (n & 3) * 128 + (n >> 2);
    float v = (k < 300) ? p.t_Wih[srow * 300 + k]
                        : ((k >= 320) ? p.t_Whh[srow * 128 + k - 320] : 0.f);
    p.Wg_t[idx] = (f16)v; return;
  }
  idx -= 229376;
  if (idx < 40960) {  // Wg_a [256][160]
    int n = idx / 160, k = idx % 160;
    int srow = (n & 3) * 64 + (n >> 2);
    float v = (k < 81) ? p.a_Wih[srow * 81 + k]
                       : ((k >= 96) ? p.a_Whh[srow * 64 + k - 96] : 0.f);
    p.Wg_a[idx] = (f16)v; return;
  }
  idx -= 40960;
  if (idx < 114688) {  // Wg_v [256][448]
    int n = idx / 448, k = idx % 448;
    int srow = (n & 3) * 64 + (n >> 2);
    float v = (k < 371) ? p.v_Wih[srow * 371 + k]
                        : ((k >= 384) ? p.v_Whh[srow * 64 + k - 384] : 0.f);
    p.Wg_v[idx] = (f16)v; return;
  }
  idx -= 114688;
  if (idx < 65536) { p.W_a1[idx] = (f16)p.aW1[idx]; return; }
  idx -= 65536;
  if (idx < 65536) { p.W_a2[idx] = (f16)p.aW2[idx]; return; }
  idx -= 65536;
  if (idx < 65536) { p.W_b1[idx] = (f16)p.bW1[idx]; return; }
  idx -= 65536;
  if (idx < 32768) { p.W_b2[idx] = (f16)p.bW2[idx]; return; }
  idx -= 32768;
  if (idx < 196608) {  // W_g1 [256][768]
    int n = idx / 768;
    p.W_g1[idx] = (f16)((n < 128) ? p.g1W1[idx] : p.g2W1[idx - 98304]);
    return;
  }
  idx -= 196608;
  if (idx < 65536) {  // W_g2 [512][128]
    int n = idx / 128;
    p.W_g2[idx] = (f16)((n < 256) ? p.g1W2[idx] : p.g2W2[idx - 32768]);
    return;
  }
  idx -= 65536;
  if (idx < 65536) { p.W_o1[idx] = (f16)p.oW1[idx]; return; }
  idx -= 65536;
  if (idx < 1024) {
    int n = idx;
    float v;
    if (n < 512)      v = p.t_b[(n & 3) * 128 + (n >> 2)];
    else if (n < 768) { int m = n - 512; v = p.a_b[(m & 3) * 64 + (m >> 2)]; }
    else              { int m = n - 768; v = p.v_b[(m & 3) * 64 + (m >> 2)]; }
    p.bg[n] = v;
  }
}

// x_p f32 [20*4096][752] -> X16 f16 [20*4096][800] with padded aligned segments
__global__ __launch_bounds__(256) void conv_x(const float* __restrict__ x,
                                              f16* __restrict__ X16) {
  int g = blockIdx.x * 256 + threadIdx.x;
  int c0 = (g % 100) * 8;
  int row = g / 100;
  const float* src = x + (size_t)row * 752;
  f16 out[8];
#pragma unroll
  for (int j = 0; j < 8; ++j) {
    int c = c0 + j;
    float v;
    if (c < 320)      v = (c < 300) ? src[c] : 0.f;
    else if (c < 416) { int s = c - 320; v = (s < 81) ? src[300 + s] : 0.f; }
    else              { int s = c - 416; v = (s < 371) ? src[381 + s] : 0.f; }
    out[j] = (f16)v;
  }
  *(f16x8*)(X16 + (size_t)row * 800 + c0) = *(f16x8*)out;
}

struct MainArgs {
  const float *x_p, *c_t, *c_a, *c_v, *mem0;
  const f16 *X16;
  const f16 *Wg_t, *Wg_a, *Wg_v, *W_a1, *W_a2, *W_b1, *W_b2, *W_g1, *W_g2, *W_o1;
  const float *bg, *a1b1, *a1b2, *a2b1, *a2b2, *g1b1, *g1b2, *g2b1, *g2b2, *ob1, *oW2, *ob2;
  float *out;
};

__device__ __forceinline__ float sigm(float x) {
  return __builtin_amdgcn_rcpf(1.f + __expf(-x));
}
__device__ __forceinline__ float ftanh(float x) {
  float t = __expf(-2.f * fabsf(x));
  float r = (1.f - t) * __builtin_amdgcn_rcpf(1.f + t);
  return copysignf(r, x);
}

// ---- gate x/h fragment load (row index lr = lane&7, 8-row block) ----------
template <int XF16, int KSX, int KSH, int XB, int KXR>
__device__ __forceinline__ void gate_load(const float* xrowf, const f16* xrow16,
                                          int hb, f16x8* ax, f16x8* ah,
                                          const f16 (*h16)[264], int lr, int lg) {
  if (XF16) {
#pragma unroll
    for (int ks = 0; ks < KSX; ++ks)
      ax[ks] = *(const f16x8*)(xrow16 + XB + 8 * lg + 32 * ks);
  } else {
#pragma unroll
    for (int ks = 0; ks < KSX; ++ks) {
      int kk = 32 * ks + 8 * lg;
      float t0[8];
      if (kk + 8 <= KXR) {
        float4 p0 = *(const float4*)(xrowf + kk);
        float4 p1 = *(const float4*)(xrowf + kk + 4);
        t0[0] = p0.x; t0[1] = p0.y; t0[2] = p0.z; t0[3] = p0.w;
        t0[4] = p1.x; t0[5] = p1.y; t0[6] = p1.z; t0[7] = p1.w;
      } else {
#pragma unroll
        for (int j = 0; j < 8; ++j) t0[j] = (kk + j < KXR) ? xrowf[kk + j] : 0.f;
      }
      f16x8 vv;
#pragma unroll
      for (int j = 0; j < 8; ++j) vv[j] = (f16)t0[j];
      ax[ks] = vv;
    }
  }
#pragma unroll
  for (int ks = 0; ks < KSH; ++ks)
    ah[ks] = *(const f16x8*)(&h16[lr][hb + 8 * lg + 32 * ks]);
}

// ---- gate GEMM, swapped operands: D rows = weight-n (=4u+gate), cols = batch
template <int KSX, int KSH, int KP>
__device__ __forceinline__ void gate_mm(const f16* Wc, const float* bg,
                                        int nc0, int n0, int cub,
                                        const f16x8* ax, const f16x8* ah,
                                        int l15, int lg,
                                        f16 (*h16)[264], float (*cS)[260],
                                        f16 (*bufA)[808]) {
#pragma unroll
  for (int i = 0; i < 8; ++i) {
    const f16* wrow = Wc + (size_t)(nc0 + 16 * i + l15) * KP + 8 * lg;
    f32x4 acc = {0.f, 0.f, 0.f, 0.f};
#pragma unroll
    for (int k = 0; k < KSX; ++k)
      acc = MFMA16(*(const f16x8*)(wrow + 32 * k), ax[k], acc);
#pragma unroll
    for (int k = 0; k < KSH; ++k)
      acc = MFMA16(*(const f16x8*)(wrow + 32 * (KSX + k)), ah[k], acc);
    if (l15 < 8) {  // D col = batch row = l15; only 8 valid rows
      const float4 bb = *(const float4*)&bg[n0 + 16 * i + 4 * lg];
      float gi = sigm(acc[0] + bb.x);
      float gf = sigm(acc[1] + bb.y);
      float gg = ftanh(acc[2] + bb.z);
      float go = sigm(acc[3] + bb.w);
      int cu = cub + ((nc0 + 16 * i) >> 2) + lg;
      float cold = cS[l15][cu];
      float cnew = gf * cold + gi * gg;
      cS[l15][cu] = cnew;
      h16[l15][cu] = (f16)(go * ftanh(cnew));
      bufA[l15][cu] = (f16)cold;        // c_star = [pre_c | cur_c]
      bufA[l15][256 + cu] = (f16)cnew;
    }
  }
}

// ---- one 16-col output tile, K = KS*32, A from LDS (A row = lr) -----------
template <int KS, int LDA>
__device__ __forceinline__ f32x4 fc_tile(const f16 (*Asrc)[LDA], int acol,
                                         const f16* Wrow, int lr, int lg) {
  f32x4 acc = {0.f, 0.f, 0.f, 0.f};
#pragma unroll
  for (int k = 0; k < KS; ++k) {
    f16x8 a = *(const f16x8*)(&Asrc[lr][acol + 8 * lg + 32 * k]);
    acc = MFMA16(a, *(const f16x8*)(Wrow + 32 * k), acc);
  }
  return acc;
}

// ---- g-hidden: K=768 from bufA, TILES 16-col tiles starting at tile st ----
template <int TILES>
__device__ __forceinline__ void ghidden_fn(const f16 (*bufA)[808], f16 (*ghid)[264],
                                           const f16* Wg1, const float* g1b1,
                                           const float* g2b1, int st, int l15,
                                           int lr, int lg) {
  f16x8 a[24];
#pragma unroll
  for (int k = 0; k < 24; ++k) a[k] = *(const f16x8*)(&bufA[lr][8 * lg + 32 * k]);
#pragma unroll
  for (int i = 0; i < TILES; ++i) {
    int nn = 16 * (st + i) + l15;
    const f16* wr = Wg1 + (size_t)nn * 768 + 8 * lg;
    f32x4 acc = {0.f, 0.f, 0.f, 0.f};
#pragma unroll
    for (int k = 0; k < 24; ++k) acc = MFMA16(a[k], *(const f16x8*)(wr + 32 * k), acc);
    if (lg < 2) {  // D row = batch = lg*4+q < 8
      float b = (nn < 128) ? g1b1[nn] : g2b1[nn - 128];
#pragma unroll
      for (int q = 0; q < 4; ++q) ghid[lg * 4 + q][nn] = (f16)fmaxf(acc[q] + b, 0.f);
    }
  }
}

template <int XF16>
__global__ __launch_bounds__(512, 4) void fused_seq(MainArgs A) {
  // 8-row block: LDS = 58,752 B -> 2 blocks/CU (4 waves/SIMD)
  __shared__ f16  h16[8][264];     // current h (fp16)
  __shared__ float cS[8][260];     // cell state f32
  __shared__ float mS[8][260];     // memory f32
  __shared__ f16  bufA[8][808];    // cstar/attended (0:512) | m fp16 (512:768)
  __shared__ f16  hid16[8][264];   // attn MLP hidden
  __shared__ f16  ghid16[8][264];  // g1|g2 hidden
  __shared__ float zf[8][516];     // attn1 logits

  const int tid = threadIdx.x;
  const int wid = tid >> 6, lane = tid & 63, l15 = lane & 15, lg = lane >> 4;
  const int lr = lane & 7;         // batch-row index for reads (dup for l15>=8)
  const int r0 = blockIdx.x * 8;

  for (int idx = tid; idx < 2048; idx += 512) {
    int r = idx >> 8, c = idx & 255, R = r0 + r;
    h16[r][c] = (f16)0.f;
    float cv = (c < 128) ? A.c_t[R * 128 + c]
                         : (c < 192 ? A.c_a[R * 64 + c - 128] : A.c_v[R * 64 + c - 192]);
    cS[r][c] = cv;
    mS[r][c] = A.mem0[R * 256 + c];
  }
  __syncthreads();

#pragma unroll 1
  for (int t = 0; t < 20; ++t) {
    // ================= STAGE G: LSTM gates (swapped-operand MFMA) ==========
    const float* xrowf = A.x_p + ((size_t)t * 4096 + r0 + lr) * 752;
    const f16* xrow16 = A.X16 + ((size_t)t * 4096 + r0 + lr) * 800;
    f16x8 ax[12], ah[4];
    if (wid < 4)
      gate_load<XF16, 10, 4, 0, 300>(xrowf, xrow16, 0, ax, ah, h16, lr, lg);
    else if (wid < 6)
      gate_load<XF16, 3, 2, 320, 81>(xrowf + 300, xrow16, 128, ax, ah, h16, lr, lg);
    else
      gate_load<XF16, 12, 2, 416, 371>(xrowf + 381, xrow16, 192, ax, ah, h16, lr, lg);
    __syncthreads();  // h frags in regs before h16/bufA/cS writes
    if (wid < 4)
      gate_mm<10, 4, 448>(A.Wg_t, A.bg, 128 * wid, 128 * wid, 0, ax, ah, l15, lg, h16, cS, bufA);
    else if (wid < 6)
      gate_mm<3, 2, 160>(A.Wg_a, A.bg, 128 * (wid - 4), 512 + 128 * (wid - 4), 128, ax, ah, l15, lg, h16, cS, bufA);
    else
      gate_mm<12, 2, 448>(A.Wg_v, A.bg, 128 * (wid - 6), 768 + 128 * (wid - 6), 192, ax, ah, l15, lg, h16, cS, bufA);
    __syncthreads();

    // ================= attn1 L1: hid = relu(cstar @ W^T + b) ===============
    {
      int n = 16 * wid;
      f32x4 acc = fc_tile<16, 808>(bufA, 0, A.W_a1 + (size_t)(n + l15) * 512 + 8 * lg, lr, lg);
      if (lg < 2) {
        float b = A.a1b1[n + l15];
#pragma unroll
        for (int q = 0; q < 4; ++q) hid16[lg * 4 + q][n + l15] = (f16)fmaxf(acc[q] + b, 0.f);
      }
    }
    __syncthreads();

    // ================= attn1 L2: logits, 4 tiles/wave ======================
    {
      f16x8 a[4];
#pragma unroll
      for (int k = 0; k < 4; ++k) a[k] = *(const f16x8*)(&hid16[lr][8 * lg + 32 * k]);
#pragma unroll
      for (int i = 0; i < 4; ++i) {
        int n = 64 * wid + 16 * i + l15;
        const f16* wr = A.W_a2 + (size_t)n * 128 + 8 * lg;
        f32x4 acc = {0.f, 0.f, 0.f, 0.f};
#pragma unroll
        for (int k = 0; k < 4; ++k) acc = MFMA16(a[k], *(const f16x8*)(wr + 32 * k), acc);
        if (lg < 2) {
          float b = A.a1b2[n];
#pragma unroll
          for (int q = 0; q < 4; ++q) zf[lg * 4 + q][n] = acc[q] + b;
        }
      }
    }
    __syncthreads();

    // ================= softmax * cstar (wave-per-row), m -> bufA[512:768] ==
    {
      int row = wid;  // 8 waves, 8 rows
      float v[8]; float mx = -1e30f;
#pragma unroll
      for (int j = 0; j < 8; ++j) { v[j] = zf[row][lane + 64 * j]; mx = fmaxf(mx, v[j]); }
#pragma unroll
      for (int m = 1; m < 64; m <<= 1) mx = fmaxf(mx, __shfl_xor(mx, m));
      float s = 0.f;
#pragma unroll
      for (int j = 0; j < 8; ++j) { v[j] = __expf(v[j] - mx); s += v[j]; }
#pragma unroll
      for (int m = 1; m < 64; m <<= 1) s += __shfl_xor(s, m);
      float inv = __builtin_amdgcn_rcpf(s);
#pragma unroll
      for (int j = 0; j < 8; ++j) {
        int c = lane + 64 * j;
        bufA[row][c] = (f16)(v[j] * inv * (float)bufA[row][c]);
      }
      for (int idx = tid; idx < 2048; idx += 512) {
        int r = idx >> 8, c = idx & 255;
        bufA[r][512 + c] = (f16)mS[r][c];
      }
    }
    __syncthreads();

    // ====== attn2 L1 (waves 6,7: 4 tiles) || g-hidden (waves 0-5) ==========
    if (wid >= 6) {
#pragma unroll
      for (int i = 0; i < 4; ++i) {
        int n = 64 * (wid - 6) + 16 * i;
        f32x4 acc = fc_tile<16, 808>(bufA, 0, A.W_b1 + (size_t)(n + l15) * 512 + 8 * lg, lr, lg);
        if (lg < 2) {
          float b = A.a2b1[n + l15];
#pragma unroll
          for (int q = 0; q < 4; ++q) hid16[lg * 4 + q][n + l15] = (f16)fmaxf(acc[q] + b, 0.f);
        }
      }
    } else if (wid < 4) {
      ghidden_fn<3>(bufA, ghid16, A.W_g1, A.g1b1, A.g2b1, 3 * wid, l15, lr, lg);
    } else {
      ghidden_fn<2>(bufA, ghid16, A.W_g1, A.g1b1, A.g2b1, 12 + 2 * (wid - 4), l15, lr, lg);
    }
    __syncthreads();

    // ====== fused: attn2 L2 + g1/g2 second layers + m-update (per-k frags) =
    {
#pragma unroll
      for (int i = 0; i < 2; ++i) {
        int n = 32 * wid + 16 * i + l15;
        const f16* wb = A.W_b2 + (size_t)n * 128 + 8 * lg;
        const f16* w1 = A.W_g2 + (size_t)n * 128 + 8 * lg;
        const f16* w2 = A.W_g2 + (size_t)(256 + n) * 128 + 8 * lg;
        f32x4 acB = {0.f, 0.f, 0.f, 0.f};
        f32x4 ac1 = {0.f, 0.f, 0.f, 0.f};
        f32x4 ac2 = {0.f, 0.f, 0.f, 0.f};
#pragma unroll
        for (int k = 0; k < 4; ++k) {
          f16x8 ha = *(const f16x8*)(&hid16[lr][8 * lg + 32 * k]);
          f16x8 ga1 = *(const f16x8*)(&ghid16[lr][8 * lg + 32 * k]);
          f16x8 ga2 = *(const f16x8*)(&ghid16[lr][128 + 8 * lg + 32 * k]);
          acB = MFMA16(ha, *(const f16x8*)(wb + 32 * k), acB);
          ac1 = MFMA16(ga1, *(const f16x8*)(w1 + 32 * k), ac1);
          ac2 = MFMA16(ga2, *(const f16x8*)(w2 + 32 * k), ac2);
        }
        if (lg < 2) {
          float bB = A.a2b2[n], b1 = A.g1b2[n], b2 = A.g2b2[n];
#pragma unroll
          for (int q = 0; q < 4; ++q) {
            int row = lg * 4 + q;
            float ch = ftanh(acB[q] + bB);
            float g1 = sigm(ac1[q] + b1);
            float g2 = sigm(ac2[q] + b2);
            mS[row][n] = g1 * mS[row][n] + g2 * ch;
          }
        }
      }
    }
    __syncthreads();
  }

  // ================= output head ==========================================
  for (int idx = tid; idx < 2048; idx += 512) {
    int r = idx >> 8, c = idx & 255;
    bufA[r][c] = h16[r][c];
    bufA[r][256 + c] = (f16)mS[r][c];
  }
  __syncthreads();
  {
    int n = 16 * wid;
    f32x4 acc = fc_tile<16, 808>(bufA, 0, A.W_o1 + (size_t)(n + l15) * 512 + 8 * lg, lr, lg);
    if (lg < 2) {
      float b = A.ob1[n + l15];
#pragma unroll
      for (int q = 0; q < 4; ++q) hid16[lg * 4 + q][n + l15] = (f16)fmaxf(acc[q] + b, 0.f);
    }
  }
  __syncthreads();
  {
    int row = wid;  // 8 rows, one wave each
    float s = (float)hid16[row][lane] * A.oW2[lane] +
              (float)hid16[row][64 + lane] * A.oW2[64 + lane];
#pragma unroll
    for (int m = 1; m < 64; m <<= 1) s += __shfl_xor(s, m);
    if (lane == 0) A.out[r0 + row] = s + A.ob2[0];
  }
}

extern "C" void kernel_launch(void* const* d_in, const int* in_sizes, int n_in,
                              void* d_out, int out_size, void* d_ws, size_t ws_size,
                              hipStream_t stream) {
  (void)in_sizes; (void)n_in; (void)out_size;
  char* w = (char*)d_ws;
  f16* Wg_t = (f16*)(w + 0);
  f16* Wg_a = (f16*)(w + 458752);
  f16* Wg_v = (f16*)(w + 540672);
  f16* W_a1 = (f16*)(w + 770048);
  f16* W_a2 = (f16*)(w + 901120);
  f16* W_b1 = (f16*)(w + 1032192);
  f16* W_b2 = (f16*)(w + 1163264);
  f16* W_g1 = (f16*)(w + 1228800);
  f16* W_g2 = (f16*)(w + 1622016);
  f16* W_o1 = (f16*)(w + 1753088);
  float* bg = (float*)(w + 1884160);
  f16* X16 = (f16*)(w + 2097152);
  const size_t X16_BYTES = (size_t)20 * 4096 * 800 * sizeof(f16);  // 131 MB
  const int use_xf16 = (ws_size >= 2097152 + X16_BYTES) ? 1 : 0;

  PackArgs pa;
  pa.t_Wih = (const float*)d_in[5];  pa.t_Whh = (const float*)d_in[6];  pa.t_b = (const float*)d_in[7];
  pa.a_Wih = (const float*)d_in[8];  pa.a_Whh = (const float*)d_in[9];  pa.a_b = (const float*)d_in[10];
  pa.v_Wih = (const float*)d_in[11]; pa.v_Whh = (const float*)d_in[12]; pa.v_b = (const float*)d_in[13];
  pa.aW1 = (const float*)d_in[14];  pa.aW2 = (const float*)d_in[16];
  pa.bW1 = (const float*)d_in[18];  pa.bW2 = (const float*)d_in[20];
  pa.g1W1 = (const float*)d_in[22]; pa.g2W1 = (const float*)d_in[26];
  pa.g1W2 = (const float*)d_in[24]; pa.g2W2 = (const float*)d_in[28];
  pa.oW1 = (const float*)d_in[30];
  pa.Wg_t = Wg_t; pa.Wg_a = Wg_a; pa.Wg_v = Wg_v; pa.W_a1 = W_a1; pa.W_a2 = W_a2;
  pa.W_b1 = W_b1; pa.W_b2 = W_b2; pa.W_g1 = W_g1; pa.W_g2 = W_g2; pa.W_o1 = W_o1;
  pa.bg = bg;
  pack_w<<<3684, 256, 0, stream>>>(pa);
  if (use_xf16) conv_x<<<32000, 256, 0, stream>>>((const float*)d_in[0], X16);

  MainArgs ma;
  ma.x_p = (const float*)d_in[0];
  ma.c_t = (const float*)d_in[1]; ma.c_a = (const float*)d_in[2]; ma.c_v = (const float*)d_in[3];
  ma.mem0 = (const float*)d_in[4];
  ma.X16 = X16;
  ma.Wg_t = Wg_t; ma.Wg_a = Wg_a; ma.Wg_v = Wg_v; ma.W_a1 = W_a1; ma.W_a2 = W_a2;
  ma.W_b1 = W_b1; ma.W_b2 = W_b2; ma.W_g1 = W_g1; ma.W_g2 = W_g2; ma.W_o1 = W_o1;
  ma.bg = bg;
  ma.a1b1 = (const float*)d_in[15]; ma.a1b2 = (const float*)d_in[17];
  ma.a2b1 = (const float*)d_in[19]; ma.a2b2 = (const float*)d_in[21];
  ma.g1b1 = (const float*)d_in[23]; ma.g1b2 = (const float*)d_in[25];
  ma.g2b1 = (const float*)d_in[27]; ma.g2b2 = (const float*)d_in[29];
  ma.ob1 = (const float*)d_in[31]; ma.oW2 = (const float*)d_in[32]; ma.ob2 = (const float*)d_in[33];
  ma.out = (float*)d_out;
  if (use_xf16) fused_seq<1><<<512, 512, 0, stream>>>(ma);
  else          fused_seq<0><<<512, 512, 0, stream>>>(ma);
}

// Round 6
// 1319.553 us; speedup vs baseline: 2.3552x; 2.3552x over previous
//
#include <hip/hip_runtime.h>
#include <math.h>

typedef _Float16 f16;
typedef f16 f16x4 __attribute__((ext_vector_type(4)));
typedef f16 f16x8 __attribute__((ext_vector_type(8)));
typedef float f32x4 __attribute__((ext_vector_type(4)));

#define MFMA16(a, b, c) __builtin_amdgcn_mfma_f32_16x16x32_f16((a), (b), (c), 0, 0, 0)

// ---------------------------------------------------------------------------
// ws layout (bytes):
//  Wg_t  fp16 [512][448]  @ 0        (x cols 0:300 pad to 320, h cols 320:448; rows n=4u+g)
//  Wg_a  fp16 [256][160]  @ 458752   (x 0:81 pad 96, h 96:160)
//  Wg_v  fp16 [256][448]  @ 540672   (x 0:371 pad 384, h 384:448)
//  W_a1  fp16 [128][512]  @ 770048
//  W_a2  fp16 [512][128]  @ 901120
//  W_b1  fp16 [128][512]  @ 1032192
//  W_b2  fp16 [256][128]  @ 1163264
//  W_g1  fp16 [256][768]  @ 1228800  rows 0:128 g1_W1, 128:256 g2_W1
//  W_g2  fp16 [512][128]  @ 1622016  rows 0:256 g1_W2, 256:512 g2_W2
//  W_o1  fp16 [128][512]  @ 1753088
//  bg    f32  [1024]      @ 1884160  gate bias, interleaved n=4u+g
//  Hst   f16 [4096][256]  @ 1888256  h carry between chunks
//  Cst   f32 [4096][256]  @ 3985408  c carry
//  Mst   f32 [4096][256]  @ 8179712  m carry
//  zx    f16 [cs*4096][1024] @ 12374016  precomputed x@Wih^T (chunk of cs steps)
// ---------------------------------------------------------------------------

struct PackArgs {
  const float *t_Wih, *t_Whh, *t_b, *a_Wih, *a_Whh, *a_b, *v_Wih, *v_Whh, *v_b;
  const float *aW1, *aW2, *bW1, *bW2, *g1W1, *g2W1, *g1W2, *g2W2, *oW1;
  f16 *Wg_t, *Wg_a, *Wg_v, *W_a1, *W_a2, *W_b1, *W_b2, *W_g1, *W_g2, *W_o1;
  float *bg;
};

__global__ __launch_bounds__(256) void pack_w(PackArgs p) {
  int idx = blockIdx.x * 256 + threadIdx.x;
  if (idx < 229376) {  // Wg_t [512][448]
    int n = idx / 448, k = idx % 448;
    int srow = (n & 3) * 128 + (n >> 2);
    float v = (k < 300) ? p.t_Wih[srow * 300 + k]
                        : ((k >= 320) ? p.t_Whh[srow * 128 + k - 320] : 0.f);
    p.Wg_t[idx] = (f16)v; return;
  }
  idx -= 229376;
  if (idx < 40960) {  // Wg_a [256][160]
    int n = idx / 160, k = idx % 160;
    int srow = (n & 3) * 64 + (n >> 2);
    float v = (k < 81) ? p.a_Wih[srow * 81 + k]
                       : ((k >= 96) ? p.a_Whh[srow * 64 + k - 96] : 0.f);
    p.Wg_a[idx] = (f16)v; return;
  }
  idx -= 40960;
  if (idx < 114688) {  // Wg_v [256][448]
    int n = idx / 448, k = idx % 448;
    int srow = (n & 3) * 64 + (n >> 2);
    float v = (k < 371) ? p.v_Wih[srow * 371 + k]
                        : ((k >= 384) ? p.v_Whh[srow * 64 + k - 384] : 0.f);
    p.Wg_v[idx] = (f16)v; return;
  }
  idx -= 114688;
  if (idx < 65536) { p.W_a1[idx] = (f16)p.aW1[idx]; return; }
  idx -= 65536;
  if (idx < 65536) { p.W_a2[idx] = (f16)p.aW2[idx]; return; }
  idx -= 65536;
  if (idx < 65536) { p.W_b1[idx] = (f16)p.bW1[idx]; return; }
  idx -= 65536;
  if (idx < 32768) { p.W_b2[idx] = (f16)p.bW2[idx]; return; }
  idx -= 32768;
  if (idx < 196608) {  // W_g1 [256][768]
    int n = idx / 768;
    p.W_g1[idx] = (f16)((n < 128) ? p.g1W1[idx] : p.g2W1[idx - 98304]);
    return;
  }
  idx -= 196608;
  if (idx < 65536) {  // W_g2 [512][128]
    int n = idx / 128;
    p.W_g2[idx] = (f16)((n < 256) ? p.g1W2[idx] : p.g2W2[idx - 32768]);
    return;
  }
  idx -= 65536;
  if (idx < 65536) { p.W_o1[idx] = (f16)p.oW1[idx]; return; }
  idx -= 65536;
  if (idx < 1024) {
    int n = idx;
    float v;
    if (n < 512)      v = p.t_b[(n & 3) * 128 + (n >> 2)];
    else if (n < 768) { int m = n - 512; v = p.a_b[(m & 3) * 64 + (m >> 2)]; }
    else              { int m = n - 768; v = p.v_b[(m & 3) * 64 + (m >> 2)]; }
    p.bg[n] = v;
  }
}

// ===========================================================================
// zx GEMM: zx[row][n] = x[row] @ Wih^T  for a chunk of cs steps.
// 128x128 output tile, BK=64, A staged f32->f16, B from packed f16 weights.
// grid = (cs*32, 8): y 0-3 = t chunks, 4-5 = a, 6-7 = v.
// ===========================================================================
struct ZxArgs { const float* x; const f16 *Wg_t, *Wg_a, *Wg_v; f16* zx; int t0; };

template <int KXR, int KIT, int XOFF, int KP>
__device__ __forceinline__ void zx_body(const float* __restrict__ x,
                                        const f16* __restrict__ Wg,
                                        f16* __restrict__ zx, int t0,
                                        int nc0, int n0g,
                                        f16 (*As)[72], f16 (*Bs)[72]) {
  const int tid = threadIdx.x;
  const int wid = tid >> 6, lane = tid & 63, l15 = lane & 15, lg = lane >> 4;
  const int mloc = blockIdx.x * 128;
  const int ar = tid >> 2;            // staging row 0..127
  const int c0 = (tid & 3) * 16;      // staging col base
  const float* xr = x + ((size_t)t0 * 4096 + mloc + ar) * 752 + XOFF;
  const f16* wr = Wg + (size_t)(nc0 + ar) * KP;
  f32x4 acc[8] = {{0.f,0.f,0.f,0.f},{0.f,0.f,0.f,0.f},{0.f,0.f,0.f,0.f},{0.f,0.f,0.f,0.f},
                  {0.f,0.f,0.f,0.f},{0.f,0.f,0.f,0.f},{0.f,0.f,0.f,0.f},{0.f,0.f,0.f,0.f}};
#pragma unroll 1
  for (int it = 0; it < KIT; ++it) {
    const int k0 = it * 64;
    f16 ta[16], tb[16];
#pragma unroll
    for (int jj = 0; jj < 4; ++jj) {
      int k = k0 + c0 + jj * 4;
      if (k + 4 <= KXR) {
        float4 pq = *(const float4*)(xr + k);
        ta[jj*4+0] = (f16)pq.x; ta[jj*4+1] = (f16)pq.y;
        ta[jj*4+2] = (f16)pq.z; ta[jj*4+3] = (f16)pq.w;
      } else {
#pragma unroll
        for (int e = 0; e < 4; ++e) ta[jj*4+e] = (f16)((k + e < KXR) ? xr[k + e] : 0.f);
      }
    }
#pragma unroll
    for (int j = 0; j < 16; ++j) {
      int k = k0 + c0 + j;
      tb[j] = (k < KXR) ? wr[k] : (f16)0.f;
    }
    __syncthreads();
    *(f16x8*)(&As[ar][c0]) = *(f16x8*)(ta);
    *(f16x8*)(&As[ar][c0 + 8]) = *(f16x8*)(ta + 8);
    *(f16x8*)(&Bs[ar][c0]) = *(f16x8*)(tb);
    *(f16x8*)(&Bs[ar][c0 + 8]) = *(f16x8*)(tb + 8);
    __syncthreads();
#pragma unroll
    for (int kf = 0; kf < 2; ++kf) {
      f16x8 a = *(const f16x8*)(&As[wid * 16 + l15][kf * 32 + 8 * lg]);
#pragma unroll
      for (int nt = 0; nt < 8; ++nt) {
        f16x8 b = *(const f16x8*)(&Bs[nt * 16 + l15][kf * 32 + 8 * lg]);
        acc[nt] = MFMA16(a, b, acc[nt]);
      }
    }
  }
#pragma unroll
  for (int nt = 0; nt < 8; ++nt) {
    int ng = n0g + nt * 16 + l15;
#pragma unroll
    for (int q = 0; q < 4; ++q) {
      int mr = mloc + wid * 16 + 4 * lg + q;
      zx[(size_t)mr * 1024 + ng] = (f16)acc[nt][q];
    }
  }
}

__global__ __launch_bounds__(512, 2) void gemm_zx(ZxArgs z) {
  __shared__ f16 As[128][72];
  __shared__ f16 Bs[128][72];
  const int y = blockIdx.y;
  if (y < 4)
    zx_body<300, 5, 0, 448>(z.x, z.Wg_t, z.zx, z.t0, y * 128, y * 128, As, Bs);
  else if (y < 6)
    zx_body<81, 2, 300, 160>(z.x, z.Wg_a, z.zx, z.t0, (y - 4) * 128, 512 + (y - 4) * 128, As, Bs);
  else
    zx_body<371, 6, 381, 448>(z.x, z.Wg_v, z.zx, z.t0, (y - 6) * 128, 768 + (y - 6) * 128, As, Bs);
}

// ===========================================================================
// Recurrent kernel
// ===========================================================================
struct MainArgs {
  const float *x_p, *c_t, *c_a, *c_v, *mem0;
  const f16 *Wg_t, *Wg_a, *Wg_v, *W_a1, *W_a2, *W_b1, *W_b2, *W_g1, *W_g2, *W_o1;
  const float *bg, *a1b1, *a1b2, *a2b1, *a2b2, *g1b1, *g1b2, *g2b1, *g2b2, *ob1, *oW2, *ob2;
  f16 *Hst; float *Cst, *Mst; const f16 *zx;
  float *out;
};

__device__ __forceinline__ float sigm(float x) {
  return __builtin_amdgcn_rcpf(1.f + __expf(-x));
}
__device__ __forceinline__ float ftanh(float x) {
  float t = __expf(-2.f * fabsf(x));
  float r = (1.f - t) * __builtin_amdgcn_rcpf(1.f + t);
  return copysignf(r, x);
}

// ---- ZX-mode gate load: 8 zx quads + h fragments ---------------------------
template <int KSH>
__device__ __forceinline__ void gload_zx(const f16* zxr, int n0,
                                         const f16 (*h16)[264], int hb,
                                         int l15, int lg, f16x4* zq, f16x8* ah) {
#pragma unroll
  for (int i = 0; i < 8; ++i) zq[i] = *(const f16x4*)(zxr + n0 + 16 * i + 4 * lg);
#pragma unroll
  for (int ks = 0; ks < KSH; ++ks)
    ah[ks] = *(const f16x8*)(&h16[l15][hb + 8 * lg + 32 * ks]);
}

// ---- ZX-mode gate GEMM (h-part only) + LSTM epilogue -----------------------
// Swapped operands: D row = n (=4u+gate) = 4*lg+q, D col = batch = l15.
template <int KSH, int KP, int HOFF>
__device__ __forceinline__ void gmm_zx(const f16* Wg, const float* bg,
                                       int nc0, int n0, int cub,
                                       const f16x4* zq, const f16x8* ah,
                                       int l15, int lg,
                                       f16 (*h16)[264], float (*cS)[260],
                                       f16 (*bufA)[808]) {
#pragma unroll
  for (int i = 0; i < 8; ++i) {
    const f16* wrow = Wg + (size_t)(nc0 + 16 * i + l15) * KP + HOFF + 8 * lg;
    f32x4 acc = {0.f, 0.f, 0.f, 0.f};
#pragma unroll
    for (int k = 0; k < KSH; ++k)
      acc = MFMA16(*(const f16x8*)(wrow + 32 * k), ah[k], acc);
    const float4 bb = *(const float4*)&bg[n0 + 16 * i + 4 * lg];
    float gi = sigm(acc[0] + (float)zq[i][0] + bb.x);
    float gf = sigm(acc[1] + (float)zq[i][1] + bb.y);
    float gg = ftanh(acc[2] + (float)zq[i][2] + bb.z);
    float go = sigm(acc[3] + (float)zq[i][3] + bb.w);
    int cu = cub + ((nc0 + 16 * i) >> 2) + lg;
    float cold = cS[l15][cu];
    float cnew = gf * cold + gi * gg;
    cS[l15][cu] = cnew;
    h16[l15][cu] = (f16)(go * ftanh(cnew));
    bufA[l15][cu] = (f16)cold;        // c_star = [pre_c | cur_c]
    bufA[l15][256 + cu] = (f16)cnew;
  }
}

// ---- fallback full gate (x f32 in-loop), proven R4 path --------------------
template <int KSX, int KSH, int KXR>
__device__ __forceinline__ void gate_load_full(const float* xrowf, int hb,
                                               f16x8* ax, f16x8* ah,
                                               const f16 (*h16)[264], int l15, int lg) {
#pragma unroll
  for (int ks = 0; ks < KSX; ++ks) {
    int kk = 32 * ks + 8 * lg;
    float t0[8];
    if (kk + 8 <= KXR) {
      float4 p0 = *(const float4*)(xrowf + kk);
      float4 p1 = *(const float4*)(xrowf + kk + 4);
      t0[0] = p0.x; t0[1] = p0.y; t0[2] = p0.z; t0[3] = p0.w;
      t0[4] = p1.x; t0[5] = p1.y; t0[6] = p1.z; t0[7] = p1.w;
    } else {
#pragma unroll
      for (int j = 0; j < 8; ++j) t0[j] = (kk + j < KXR) ? xrowf[kk + j] : 0.f;
    }
    f16x8 vv;
#pragma unroll
    for (int j = 0; j < 8; ++j) vv[j] = (f16)t0[j];
    ax[ks] = vv;
  }
#pragma unroll
  for (int ks = 0; ks < KSH; ++ks)
    ah[ks] = *(const f16x8*)(&h16[l15][hb + 8 * lg + 32 * ks]);
}

template <int KSX, int KSH, int KP>
__device__ __forceinline__ void gate_mm_full(const f16* Wc, const float* bg,
                                             int nc0, int n0, int cub,
                                             const f16x8* ax, const f16x8* ah,
                                             int l15, int lg,
                                             f16 (*h16)[264], float (*cS)[260],
                                             f16 (*bufA)[808]) {
#pragma unroll
  for (int i = 0; i < 8; ++i) {
    const f16* wrow = Wc + (size_t)(nc0 + 16 * i + l15) * KP + 8 * lg;
    f32x4 acc = {0.f, 0.f, 0.f, 0.f};
#pragma unroll
    for (int k = 0; k < KSX; ++k)
      acc = MFMA16(*(const f16x8*)(wrow + 32 * k), ax[k], acc);
#pragma unroll
    for (int k = 0; k < KSH; ++k)
      acc = MFMA16(*(const f16x8*)(wrow + 32 * (KSX + k)), ah[k], acc);
    const float4 bb = *(const float4*)&bg[n0 + 16 * i + 4 * lg];
    float gi = sigm(acc[0] + bb.x);
    float gf = sigm(acc[1] + bb.y);
    float gg = ftanh(acc[2] + bb.z);
    float go = sigm(acc[3] + bb.w);
    int cu = cub + ((nc0 + 16 * i) >> 2) + lg;
    float cold = cS[l15][cu];
    float cnew = gf * cold + gi * gg;
    cS[l15][cu] = cnew;
    h16[l15][cu] = (f16)(go * ftanh(cnew));
    bufA[l15][cu] = (f16)cold;
    bufA[l15][256 + cu] = (f16)cnew;
  }
}

// ---- one 16-col tile, per-k loads (no batching: no spill) ------------------
template <int KS, int LDA>
__device__ __forceinline__ f32x4 fc_tile(const f16 (*Asrc)[LDA], int acol,
                                         const f16* Wrow, int l15, int lg) {
  f32x4 acc = {0.f, 0.f, 0.f, 0.f};
#pragma unroll
  for (int k = 0; k < KS; ++k) {
    f16x8 a = *(const f16x8*)(&Asrc[l15][acol + 8 * lg + 32 * k]);
    acc = MFMA16(a, *(const f16x8*)(Wrow + 32 * k), acc);
  }
  return acc;
}

template <int ZX>
__global__ __launch_bounds__(512, 2) void fused_seq(MainArgs A, int t0, int cs,
                                                    int first, int last) {
  __shared__ f16  h16[16][264];
  __shared__ float cS[16][260];
  __shared__ float mS[16][260];
  __shared__ f16  bufA[16][808];    // cstar/attended (0:512) | m fp16 (512:768)
  __shared__ f16  hid16[16][264];
  __shared__ f16  ghid16[16][264];
  __shared__ float zf[16][516];

  const int tid = threadIdx.x;
  const int wid = tid >> 6, lane = tid & 63, l15 = lane & 15, lg = lane >> 4;
  const int r0 = blockIdx.x * 16;

  if (first) {
    for (int idx = tid; idx < 4096; idx += 512) {
      int r = idx >> 8, c = idx & 255, R = r0 + r;
      h16[r][c] = (f16)0.f;
      float cv = (c < 128) ? A.c_t[R * 128 + c]
                           : (c < 192 ? A.c_a[R * 64 + c - 128] : A.c_v[R * 64 + c - 192]);
      cS[r][c] = cv;
      mS[r][c] = A.mem0[R * 256 + c];
    }
  } else {
    for (int idx = tid; idx < 4096; idx += 512) {
      int r = idx >> 8, c = idx & 255;
      size_t g = (size_t)(r0 + r) * 256 + c;
      h16[r][c] = A.Hst[g];
      cS[r][c] = A.Cst[g];
      mS[r][c] = A.Mst[g];
    }
  }
  __syncthreads();

#pragma unroll 1
  for (int ts = 0; ts < cs; ++ts) {
    // ================= STAGE G: LSTM gates =================================
    if (ZX) {
      const f16* zxr = A.zx + ((size_t)ts * 4096 + r0 + l15) * 1024;
      f16x4 zq[8]; f16x8 ah[4];
      if (wid < 4)      gload_zx<4>(zxr, 128 * wid, h16, 0, l15, lg, zq, ah);
      else if (wid < 6) gload_zx<2>(zxr, 512 + 128 * (wid - 4), h16, 128, l15, lg, zq, ah);
      else              gload_zx<2>(zxr, 768 + 128 * (wid - 6), h16, 192, l15, lg, zq, ah);
      __syncthreads();
      if (wid < 4)
        gmm_zx<4, 448, 320>(A.Wg_t, A.bg, 128 * wid, 128 * wid, 0, zq, ah, l15, lg, h16, cS, bufA);
      else if (wid < 6)
        gmm_zx<2, 160, 96>(A.Wg_a, A.bg, 128 * (wid - 4), 512 + 128 * (wid - 4), 128, zq, ah, l15, lg, h16, cS, bufA);
      else
        gmm_zx<2, 448, 384>(A.Wg_v, A.bg, 128 * (wid - 6), 768 + 128 * (wid - 6), 192, zq, ah, l15, lg, h16, cS, bufA);
    } else {
      const float* xrowf = A.x_p + ((size_t)(t0 + ts) * 4096 + r0 + l15) * 752;
      f16x8 ax[12], ah[4];
      if (wid < 4)      gate_load_full<10, 4, 300>(xrowf, 0, ax, ah, h16, l15, lg);
      else if (wid < 6) gate_load_full<3, 2, 81>(xrowf + 300, 128, ax, ah, h16, l15, lg);
      else              gate_load_full<12, 2, 371>(xrowf + 381, 192, ax, ah, h16, l15, lg);
      __syncthreads();
      if (wid < 4)
        gate_mm_full<10, 4, 448>(A.Wg_t, A.bg, 128 * wid, 128 * wid, 0, ax, ah, l15, lg, h16, cS, bufA);
      else if (wid < 6)
        gate_mm_full<3, 2, 160>(A.Wg_a, A.bg, 128 * (wid - 4), 512 + 128 * (wid - 4), 128, ax, ah, l15, lg, h16, cS, bufA);
      else
        gate_mm_full<12, 2, 448>(A.Wg_v, A.bg, 128 * (wid - 6), 768 + 128 * (wid - 6), 192, ax, ah, l15, lg, h16, cS, bufA);
    }
    __syncthreads();

    // ================= attn1 L1: hid = relu(cstar @ W^T + b) ===============
    {
      int n = 16 * wid;
      f32x4 acc = fc_tile<16, 808>(bufA, 0, A.W_a1 + (size_t)(n + l15) * 512 + 8 * lg, l15, lg);
      float b = A.a1b1[n + l15];
#pragma unroll
      for (int q = 0; q < 4; ++q) hid16[lg * 4 + q][n + l15] = (f16)fmaxf(acc[q] + b, 0.f);
    }
    __syncthreads();

    // ================= attn1 L2: logits, 4 tiles/wave ======================
    {
#pragma unroll
      for (int i = 0; i < 4; ++i) {
        int n = 64 * wid + 16 * i + l15;
        f32x4 acc = fc_tile<4, 264>(hid16, 0, A.W_a2 + (size_t)n * 128 + 8 * lg, l15, lg);
        float b = A.a1b2[n];
#pragma unroll
        for (int q = 0; q < 4; ++q) zf[lg * 4 + q][n] = acc[q] + b;
      }
    }
    __syncthreads();

    // ================= softmax * cstar (in place), m -> bufA[512:768] ======
    {
      int row = tid >> 5, c0 = tid & 31;
      float v[16]; float mx = -1e30f;
#pragma unroll
      for (int j = 0; j < 16; ++j) { v[j] = zf[row][c0 + 32 * j]; mx = fmaxf(mx, v[j]); }
#pragma unroll
      for (int m = 1; m < 32; m <<= 1) mx = fmaxf(mx, __shfl_xor(mx, m));
      float s = 0.f;
#pragma unroll
      for (int j = 0; j < 16; ++j) { v[j] = __expf(v[j] - mx); s += v[j]; }
#pragma unroll
      for (int m = 1; m < 32; m <<= 1) s += __shfl_xor(s, m);
      float inv = __builtin_amdgcn_rcpf(s);
#pragma unroll
      for (int j = 0; j < 16; ++j) {
        int c = c0 + 32 * j;
        bufA[row][c] = (f16)(v[j] * inv * (float)bufA[row][c]);
      }
      for (int idx = tid; idx < 4096; idx += 512) {
        int r = idx >> 8, c = idx & 255;
        bufA[r][512 + c] = (f16)mS[r][c];
      }
    }
    __syncthreads();

    // ====== attn2 L1 (waves 6,7: 4 tiles) || g-hidden (waves 0-5) ==========
    if (wid >= 6) {
#pragma unroll
      for (int i = 0; i < 4; ++i) {
        int n = 64 * (wid - 6) + 16 * i;
        f32x4 acc = fc_tile<16, 808>(bufA, 0, A.W_b1 + (size_t)(n + l15) * 512 + 8 * lg, l15, lg);
        float b = A.a2b1[n + l15];
#pragma unroll
        for (int q = 0; q < 4; ++q) hid16[lg * 4 + q][n + l15] = (f16)fmaxf(acc[q] + b, 0.f);
      }
    } else {
      int st = (wid < 4) ? 3 * wid : 12 + 2 * (wid - 4);
      int cnt = (wid < 4) ? 3 : 2;
#pragma unroll
      for (int i = 0; i < 3; ++i) if (i < cnt) {
        int nn = 16 * (st + i) + l15;
        f32x4 acc = fc_tile<24, 808>(bufA, 0, A.W_g1 + (size_t)nn * 768 + 8 * lg, l15, lg);
        float b = (nn < 128) ? A.g1b1[nn] : A.g2b1[nn - 128];
#pragma unroll
        for (int q = 0; q < 4; ++q) ghid16[lg * 4 + q][nn] = (f16)fmaxf(acc[q] + b, 0.f);
      }
    }
    __syncthreads();

    // ====== fused: attn2 L2 + g1/g2 second layers + m-update (per-k loads) =
    {
#pragma unroll
      for (int i = 0; i < 2; ++i) {
        int n = 32 * wid + 16 * i + l15;
        const f16* wb = A.W_b2 + (size_t)n * 128 + 8 * lg;
        const f16* w1 = A.W_g2 + (size_t)n * 128 + 8 * lg;
        const f16* w2 = A.W_g2 + (size_t)(256 + n) * 128 + 8 * lg;
        f32x4 acB = {0.f, 0.f, 0.f, 0.f};
        f32x4 ac1 = {0.f, 0.f, 0.f, 0.f};
        f32x4 ac2 = {0.f, 0.f, 0.f, 0.f};
#pragma unroll
        for (int k = 0; k < 4; ++k) {
          f16x8 ha = *(const f16x8*)(&hid16[l15][8 * lg + 32 * k]);
          f16x8 ga1 = *(const f16x8*)(&ghid16[l15][8 * lg + 32 * k]);
          f16x8 ga2 = *(const f16x8*)(&ghid16[l15][128 + 8 * lg + 32 * k]);
          acB = MFMA16(ha, *(const f16x8*)(wb + 32 * k), acB);
          ac1 = MFMA16(ga1, *(const f16x8*)(w1 + 32 * k), ac1);
          ac2 = MFMA16(ga2, *(const f16x8*)(w2 + 32 * k), ac2);
        }
        float bB = A.a2b2[n], b1 = A.g1b2[n], b2 = A.g2b2[n];
#pragma unroll
        for (int q = 0; q < 4; ++q) {
          int row = lg * 4 + q;
          float ch = ftanh(acB[q] + bB);
          float g1 = sigm(ac1[q] + b1);
          float g2 = sigm(ac2[q] + b2);
          mS[row][n] = g1 * mS[row][n] + g2 * ch;
        }
      }
    }
    __syncthreads();
  }

  if (last) {
    // ================= output head ========================================
    for (int idx = tid; idx < 4096; idx += 512) {
      int r = idx >> 8, c = idx & 255;
      bufA[r][c] = h16[r][c];
      bufA[r][256 + c] = (f16)mS[r][c];
    }
    __syncthreads();
    {
      int n = 16 * wid;
      f32x4 acc = fc_tile<16, 808>(bufA, 0, A.W_o1 + (size_t)(n + l15) * 512 + 8 * lg, l15, lg);
      float b = A.ob1[n + l15];
#pragma unroll
      for (int q = 0; q < 4; ++q) hid16[lg * 4 + q][n + l15] = (f16)fmaxf(acc[q] + b, 0.f);
    }
    __syncthreads();
    {
      int row = tid >> 5, c0 = tid & 31;
      float s = 0.f;
#pragma unroll
      for (int j = 0; j < 4; ++j) { int k = c0 + 32 * j; s += (float)hid16[row][k] * A.oW2[k]; }
#pragma unroll
      for (int m = 1; m < 32; m <<= 1) s += __shfl_xor(s, m);
      if (c0 == 0) A.out[r0 + row] = s + A.ob2[0];
    }
  } else {
    // carry state to next chunk
    for (int idx = tid; idx < 4096; idx += 512) {
      int r = idx >> 8, c = idx & 255;
      size_t g = (size_t)(r0 + r) * 256 + c;
      A.Hst[g] = h16[r][c];
      A.Cst[g] = cS[r][c];
      A.Mst[g] = mS[r][c];
    }
  }
}

extern "C" void kernel_launch(void* const* d_in, const int* in_sizes, int n_in,
                              void* d_out, int out_size, void* d_ws, size_t ws_size,
                              hipStream_t stream) {
  (void)in_sizes; (void)n_in; (void)out_size;
  char* w = (char*)d_ws;
  f16* Wg_t = (f16*)(w + 0);
  f16* Wg_a = (f16*)(w + 458752);
  f16* Wg_v = (f16*)(w + 540672);
  f16* W_a1 = (f16*)(w + 770048);
  f16* W_a2 = (f16*)(w + 901120);
  f16* W_b1 = (f16*)(w + 1032192);
  f16* W_b2 = (f16*)(w + 1163264);
  f16* W_g1 = (f16*)(w + 1228800);
  f16* W_g2 = (f16*)(w + 1622016);
  f16* W_o1 = (f16*)(w + 1753088);
  float* bg = (float*)(w + 1884160);
  f16* Hst = (f16*)(w + 1888256);
  float* Cst = (float*)(w + 3985408);
  float* Mst = (float*)(w + 8179712);
  f16* zx = (f16*)(w + 12374016);

  // chunk size: largest divisor of 20 whose zx buffer fits in ws
  size_t avail = (ws_size > 12374016) ? ws_size - 12374016 : 0;
  const size_t per_step = (size_t)4096 * 1024 * 2;
  int cs = 0;
  const int divs[6] = {20, 10, 5, 4, 2, 1};
  for (int i = 0; i < 6; ++i)
    if ((size_t)divs[i] * per_step <= avail) { cs = divs[i]; break; }

  PackArgs pa;
  pa.t_Wih = (const float*)d_in[5];  pa.t_Whh = (const float*)d_in[6];  pa.t_b = (const float*)d_in[7];
  pa.a_Wih = (const float*)d_in[8];  pa.a_Whh = (const float*)d_in[9];  pa.a_b = (const float*)d_in[10];
  pa.v_Wih = (const float*)d_in[11]; pa.v_Whh = (const float*)d_in[12]; pa.v_b = (const float*)d_in[13];
  pa.aW1 = (const float*)d_in[14];  pa.aW2 = (const float*)d_in[16];
  pa.bW1 = (const float*)d_in[18];  pa.bW2 = (const float*)d_in[20];
  pa.g1W1 = (const float*)d_in[22]; pa.g2W1 = (const float*)d_in[26];
  pa.g1W2 = (const float*)d_in[24]; pa.g2W2 = (const float*)d_in[28];
  pa.oW1 = (const float*)d_in[30];
  pa.Wg_t = Wg_t; pa.Wg_a = Wg_a; pa.Wg_v = Wg_v; pa.W_a1 = W_a1; pa.W_a2 = W_a2;
  pa.W_b1 = W_b1; pa.W_b2 = W_b2; pa.W_g1 = W_g1; pa.W_g2 = W_g2; pa.W_o1 = W_o1;
  pa.bg = bg;
  pack_w<<<3684, 256, 0, stream>>>(pa);

  MainArgs ma;
  ma.x_p = (const float*)d_in[0];
  ma.c_t = (const float*)d_in[1]; ma.c_a = (const float*)d_in[2]; ma.c_v = (const float*)d_in[3];
  ma.mem0 = (const float*)d_in[4];
  ma.Wg_t = Wg_t; ma.Wg_a = Wg_a; ma.Wg_v = Wg_v; ma.W_a1 = W_a1; ma.W_a2 = W_a2;
  ma.W_b1 = W_b1; ma.W_b2 = W_b2; ma.W_g1 = W_g1; ma.W_g2 = W_g2; ma.W_o1 = W_o1;
  ma.bg = bg;
  ma.a1b1 = (const float*)d_in[15]; ma.a1b2 = (const float*)d_in[17];
  ma.a2b1 = (const float*)d_in[19]; ma.a2b2 = (const float*)d_in[21];
  ma.g1b1 = (const float*)d_in[23]; ma.g1b2 = (const float*)d_in[25];
  ma.g2b1 = (const float*)d_in[27]; ma.g2b2 = (const float*)d_in[29];
  ma.ob1 = (const float*)d_in[31]; ma.oW2 = (const float*)d_in[32]; ma.ob2 = (const float*)d_in[33];
  ma.Hst = Hst; ma.Cst = Cst; ma.Mst = Mst; ma.zx = zx;
  ma.out = (float*)d_out;

  if (cs > 0) {
    for (int t0 = 0; t0 < 20; t0 += cs) {
      ZxArgs za; za.x = (const float*)d_in[0];
      za.Wg_t = Wg_t; za.Wg_a = Wg_a; za.Wg_v = Wg_v; za.zx = zx; za.t0 = t0;
      gemm_zx<<<dim3(cs * 32, 8), 512, 0, stream>>>(za);
      fused_seq<1><<<256, 512, 0, stream>>>(ma, t0, cs, t0 == 0 ? 1 : 0,
                                            (t0 + cs >= 20) ? 1 : 0);
    }
  } else {
    fused_seq<0><<<256, 512, 0, stream>>>(ma, 0, 20, 1, 1);
  }
}

// Round 7
// 1030.347 us; speedup vs baseline: 3.0163x; 1.2807x over previous
//
#include <hip/hip_runtime.h>
#include <math.h>

typedef _Float16 f16;
typedef f16 f16x4 __attribute__((ext_vector_type(4)));
typedef f16 f16x8 __attribute__((ext_vector_type(8)));
typedef float f32x4 __attribute__((ext_vector_type(4)));

#define MFMA16(a, b, c) __builtin_amdgcn_mfma_f32_16x16x32_f16((a), (b), (c), 0, 0, 0)

// ---------------------------------------------------------------------------
// ws layout (bytes):
//  Wg_t  fp16 [512][448]  @ 0        (x cols 0:300 pad to 320, h cols 320:448; rows n=4u+g)
//  Wg_a  fp16 [256][160]  @ 458752   (x 0:81 pad 96, h 96:160)
//  Wg_v  fp16 [256][448]  @ 540672   (x 0:371 pad 384, h 384:448)
//  W_a1  fp16 [128][512]  @ 770048
//  W_a2  fp16 [512][128]  @ 901120
//  W_b1  fp16 [128][512]  @ 1032192
//  W_b2  fp16 [256][128]  @ 1163264
//  W_g1  fp16 [256][768]  @ 1228800  rows 0:128 g1_W1, 128:256 g2_W1
//  W_g2  fp16 [512][128]  @ 1622016  rows 0:256 g1_W2, 256:512 g2_W2
//  W_o1  fp16 [128][512]  @ 1753088
//  bg    f32  [1024]      @ 1884160  gate bias, interleaved n=4u+g
//  Hst   f16 [4096][256]  @ 1888256  h carry between chunks
//  Cst   f32 [4096][256]  @ 3985408  c carry
//  Mst   f32 [4096][256]  @ 8179712  m carry
//  zx    f16 [cs*4096][1024] @ 12374016  precomputed x@Wih^T (chunk of cs steps)
// ---------------------------------------------------------------------------

struct PackArgs {
  const float *t_Wih, *t_Whh, *t_b, *a_Wih, *a_Whh, *a_b, *v_Wih, *v_Whh, *v_b;
  const float *aW1, *aW2, *bW1, *bW2, *g1W1, *g2W1, *g1W2, *g2W2, *oW1;
  f16 *Wg_t, *Wg_a, *Wg_v, *W_a1, *W_a2, *W_b1, *W_b2, *W_g1, *W_g2, *W_o1;
  float *bg;
};

__global__ __launch_bounds__(256) void pack_w(PackArgs p) {
  int idx = blockIdx.x * 256 + threadIdx.x;
  if (idx < 229376) {  // Wg_t [512][448]
    int n = idx / 448, k = idx % 448;
    int srow = (n & 3) * 128 + (n >> 2);
    float v = (k < 300) ? p.t_Wih[srow * 300 + k]
                        : ((k >= 320) ? p.t_Whh[srow * 128 + k - 320] : 0.f);
    p.Wg_t[idx] = (f16)v; return;
  }
  idx -= 229376;
  if (idx < 40960) {  // Wg_a [256][160]
    int n = idx / 160, k = idx % 160;
    int srow = (n & 3) * 64 + (n >> 2);
    float v = (k < 81) ? p.a_Wih[srow * 81 + k]
                       : ((k >= 96) ? p.a_Whh[srow * 64 + k - 96] : 0.f);
    p.Wg_a[idx] = (f16)v; return;
  }
  idx -= 40960;
  if (idx < 114688) {  // Wg_v [256][448]
    int n = idx / 448, k = idx % 448;
    int srow = (n & 3) * 64 + (n >> 2);
    float v = (k < 371) ? p.v_Wih[srow * 371 + k]
                        : ((k >= 384) ? p.v_Whh[srow * 64 + k - 384] : 0.f);
    p.Wg_v[idx] = (f16)v; return;
  }
  idx -= 114688;
  if (idx < 65536) { p.W_a1[idx] = (f16)p.aW1[idx]; return; }
  idx -= 65536;
  if (idx < 65536) { p.W_a2[idx] = (f16)p.aW2[idx]; return; }
  idx -= 65536;
  if (idx < 65536) { p.W_b1[idx] = (f16)p.bW1[idx]; return; }
  idx -= 65536;
  if (idx < 32768) { p.W_b2[idx] = (f16)p.bW2[idx]; return; }
  idx -= 32768;
  if (idx < 196608) {  // W_g1 [256][768]
    int n = idx / 768;
    p.W_g1[idx] = (f16)((n < 128) ? p.g1W1[idx] : p.g2W1[idx - 98304]);
    return;
  }
  idx -= 196608;
  if (idx < 65536) {  // W_g2 [512][128]
    int n = idx / 128;
    p.W_g2[idx] = (f16)((n < 256) ? p.g1W2[idx] : p.g2W2[idx - 32768]);
    return;
  }
  idx -= 65536;
  if (idx < 65536) { p.W_o1[idx] = (f16)p.oW1[idx]; return; }
  idx -= 65536;
  if (idx < 1024) {
    int n = idx;
    float v;
    if (n < 512)      v = p.t_b[(n & 3) * 128 + (n >> 2)];
    else if (n < 768) { int m = n - 512; v = p.a_b[(m & 3) * 64 + (m >> 2)]; }
    else              { int m = n - 768; v = p.v_b[(m & 3) * 64 + (m >> 2)]; }
    p.bg[n] = v;
  }
}

// ===========================================================================
// zx GEMM v2: 32-row blocks, x staged ONCE into LDS (f16, padded layout),
// each wave owns a 128-wide n-slice; W loads batched 4 tiles at a time.
// grid = cs*128 blocks.
// ===========================================================================
struct ZxArgs { const float* x; const f16 *Wg_t, *Wg_a, *Wg_v; f16* zx; int t0; };

template <int KS, int KP, int XOFF>
__device__ __forceinline__ void zx_wave(const f16* __restrict__ Wg, int nc0, int n0g,
                                        const f16 (*Xs)[808], f16* __restrict__ zx,
                                        int mloc, int l15, int lg) {
#pragma unroll 1
  for (int half = 0; half < 2; ++half) {
    f32x4 acc[8];
#pragma unroll
    for (int j = 0; j < 8; ++j) acc[j] = (f32x4){0.f, 0.f, 0.f, 0.f};
#pragma unroll 1
    for (int ks = 0; ks < KS; ++ks) {
      f16x8 w[4];
#pragma unroll
      for (int i = 0; i < 4; ++i)
        w[i] = *(const f16x8*)(Wg + (size_t)(nc0 + 64 * half + 16 * i + l15) * KP + 32 * ks + 8 * lg);
      f16x8 a0 = *(const f16x8*)(&Xs[l15][XOFF + 32 * ks + 8 * lg]);
      f16x8 a1 = *(const f16x8*)(&Xs[16 + l15][XOFF + 32 * ks + 8 * lg]);
#pragma unroll
      for (int i = 0; i < 4; ++i) {
        acc[i] = MFMA16(a0, w[i], acc[i]);
        acc[4 + i] = MFMA16(a1, w[i], acc[4 + i]);
      }
    }
#pragma unroll
    for (int mt = 0; mt < 2; ++mt)
#pragma unroll
      for (int i = 0; i < 4; ++i) {
        int ng = n0g + 64 * half + 16 * i + l15;
#pragma unroll
        for (int q = 0; q < 4; ++q)
          zx[(size_t)(mloc + mt * 16 + 4 * lg + q) * 1024 + ng] = (f16)acc[mt * 4 + i][q];
      }
  }
}

__global__ __launch_bounds__(512, 2) void gemm_zx(ZxArgs z) {
  __shared__ f16 Xs[32][808];
  const int tid = threadIdx.x, wid = tid >> 6, lane = tid & 63, l15 = lane & 15, lg = lane >> 4;
  const int mloc = blockIdx.x * 32;
  {
    int r = tid >> 4;  // 0..31
    const float* xr = z.x + ((size_t)z.t0 * 4096 + mloc + r) * 752;
    for (int c = tid & 15; c < 800; c += 16) {
      float v;
      if (c < 320)      v = (c < 300) ? xr[c] : 0.f;
      else if (c < 416) { int s = c - 320; v = (s < 81) ? xr[300 + s] : 0.f; }
      else              { int s = c - 416; v = (s < 371) ? xr[381 + s] : 0.f; }
      Xs[r][c] = (f16)v;
    }
  }
  __syncthreads();
  if (wid < 4)
    zx_wave<10, 448, 0>(z.Wg_t, 128 * wid, 128 * wid, Xs, z.zx, mloc, l15, lg);
  else if (wid < 6)
    zx_wave<3, 160, 320>(z.Wg_a, 128 * (wid - 4), 512 + 128 * (wid - 4), Xs, z.zx, mloc, l15, lg);
  else
    zx_wave<12, 448, 416>(z.Wg_v, 128 * (wid - 6), 768 + 128 * (wid - 6), Xs, z.zx, mloc, l15, lg);
}

// ===========================================================================
// Recurrent kernel
// ===========================================================================
struct MainArgs {
  const float *x_p, *c_t, *c_a, *c_v, *mem0;
  const f16 *Wg_t, *Wg_a, *Wg_v, *W_a1, *W_a2, *W_b1, *W_b2, *W_g1, *W_g2, *W_o1;
  const float *bg, *a1b1, *a1b2, *a2b1, *a2b2, *g1b1, *g1b2, *g2b1, *g2b2, *ob1, *oW2, *ob2;
  f16 *Hst; float *Cst, *Mst; const f16 *zx;
  float *out;
};

__device__ __forceinline__ float sigm(float x) {
  return __builtin_amdgcn_rcpf(1.f + __expf(-x));
}
__device__ __forceinline__ float ftanh(float x) {
  float t = __expf(-2.f * fabsf(x));
  float r = (1.f - t) * __builtin_amdgcn_rcpf(1.f + t);
  return copysignf(r, x);
}

// ---- batched fc tile: W loads grouped (1 latency per <=8 loads), A from LDS
template <int KS, int LDA>
__device__ __forceinline__ f32x4 fc_tileB(const f16 (*Asrc)[LDA], int acol,
                                          const f16* Wrow, int l15, int lg) {
  f32x4 acc = {0.f, 0.f, 0.f, 0.f};
  constexpr int GB = (KS < 8) ? KS : 8;
  constexpr int G = (KS + GB - 1) / GB;
#pragma unroll
  for (int g = 0; g < G; ++g) {
    f16x8 w[GB];
#pragma unroll
    for (int j = 0; j < GB; ++j) w[j] = *(const f16x8*)(Wrow + 32 * (g * GB + j));
#pragma unroll
    for (int j = 0; j < GB; ++j) {
      f16x8 a = *(const f16x8*)(&Asrc[l15][acol + 8 * lg + 32 * (g * GB + j)]);
      acc = MFMA16(a, w[j], acc);
    }
  }
  return acc;
}

// ---- gate h-fragment load (pre-barrier) ------------------------------------
template <int KSH>
__device__ __forceinline__ void gload_zx(const f16 (*h16)[264], int hb,
                                         int l15, int lg, f16x8* ah) {
#pragma unroll
  for (int ks = 0; ks < KSH; ++ks)
    ah[ks] = *(const f16x8*)(&h16[l15][hb + 8 * lg + 32 * ks]);
}

// ---- gate GEMM (h-part only), tile pairs with batched W, z from global zx --
template <int KSH, int KP, int HOFF>
__device__ __forceinline__ void gmm_zxB(const f16* Wg, const float* bg, const f16* zxr,
                                        int nc0, int n0, int cub,
                                        const f16x8* ah, int l15, int lg,
                                        f16 (*h16)[264], float (*cS)[260],
                                        f16 (*bufA)[808]) {
#pragma unroll 1
  for (int p = 0; p < 4; ++p) {
    const f16* r0 = Wg + (size_t)(nc0 + 32 * p + l15) * KP + HOFF + 8 * lg;
    const f16* r1 = r0 + (size_t)16 * KP;
    f16x8 w0[KSH], w1[KSH];
#pragma unroll
    for (int k = 0; k < KSH; ++k) {
      w0[k] = *(const f16x8*)(r0 + 32 * k);
      w1[k] = *(const f16x8*)(r1 + 32 * k);
    }
    f16x4 z0 = *(const f16x4*)(zxr + n0 + 32 * p + 4 * lg);
    f16x4 z1 = *(const f16x4*)(zxr + n0 + 32 * p + 16 + 4 * lg);
    f32x4 a0 = {0.f, 0.f, 0.f, 0.f}, a1 = {0.f, 0.f, 0.f, 0.f};
#pragma unroll
    for (int k = 0; k < KSH; ++k) {
      a0 = MFMA16(w0[k], ah[k], a0);
      a1 = MFMA16(w1[k], ah[k], a1);
    }
    const float4 b0 = *(const float4*)&bg[n0 + 32 * p + 4 * lg];
    const float4 b1 = *(const float4*)&bg[n0 + 32 * p + 16 + 4 * lg];
    {
      float gi = sigm(a0[0] + (float)z0[0] + b0.x);
      float gf = sigm(a0[1] + (float)z0[1] + b0.y);
      float gg = ftanh(a0[2] + (float)z0[2] + b0.z);
      float go = sigm(a0[3] + (float)z0[3] + b0.w);
      int cu = cub + ((nc0 + 32 * p) >> 2) + lg;
      float cold = cS[l15][cu];
      float cnew = gf * cold + gi * gg;
      cS[l15][cu] = cnew;
      h16[l15][cu] = (f16)(go * ftanh(cnew));
      bufA[l15][cu] = (f16)cold;
      bufA[l15][256 + cu] = (f16)cnew;
    }
    {
      float gi = sigm(a1[0] + (float)z1[0] + b1.x);
      float gf = sigm(a1[1] + (float)z1[1] + b1.y);
      float gg = ftanh(a1[2] + (float)z1[2] + b1.z);
      float go = sigm(a1[3] + (float)z1[3] + b1.w);
      int cu = cub + ((nc0 + 32 * p + 16) >> 2) + lg;
      float cold = cS[l15][cu];
      float cnew = gf * cold + gi * gg;
      cS[l15][cu] = cnew;
      h16[l15][cu] = (f16)(go * ftanh(cnew));
      bufA[l15][cu] = (f16)cold;
      bufA[l15][256 + cu] = (f16)cnew;
    }
  }
}

// ---- fallback full gate (x f32 in-loop), proven R4 path --------------------
template <int KSX, int KSH, int KXR>
__device__ __forceinline__ void gate_load_full(const float* xrowf, int hb,
                                               f16x8* ax, f16x8* ah,
                                               const f16 (*h16)[264], int l15, int lg) {
#pragma unroll
  for (int ks = 0; ks < KSX; ++ks) {
    int kk = 32 * ks + 8 * lg;
    float t0[8];
    if (kk + 8 <= KXR) {
      float4 p0 = *(const float4*)(xrowf + kk);
      float4 p1 = *(const float4*)(xrowf + kk + 4);
      t0[0] = p0.x; t0[1] = p0.y; t0[2] = p0.z; t0[3] = p0.w;
      t0[4] = p1.x; t0[5] = p1.y; t0[6] = p1.z; t0[7] = p1.w;
    } else {
#pragma unroll
      for (int j = 0; j < 8; ++j) t0[j] = (kk + j < KXR) ? xrowf[kk + j] : 0.f;
    }
    f16x8 vv;
#pragma unroll
    for (int j = 0; j < 8; ++j) vv[j] = (f16)t0[j];
    ax[ks] = vv;
  }
#pragma unroll
  for (int ks = 0; ks < KSH; ++ks)
    ah[ks] = *(const f16x8*)(&h16[l15][hb + 8 * lg + 32 * ks]);
}

template <int KSX, int KSH, int KP>
__device__ __forceinline__ void gate_mm_full(const f16* Wc, const float* bg,
                                             int nc0, int n0, int cub,
                                             const f16x8* ax, const f16x8* ah,
                                             int l15, int lg,
                                             f16 (*h16)[264], float (*cS)[260],
                                             f16 (*bufA)[808]) {
#pragma unroll
  for (int i = 0; i < 8; ++i) {
    const f16* wrow = Wc + (size_t)(nc0 + 16 * i + l15) * KP + 8 * lg;
    f32x4 acc = {0.f, 0.f, 0.f, 0.f};
#pragma unroll
    for (int k = 0; k < KSX; ++k)
      acc = MFMA16(*(const f16x8*)(wrow + 32 * k), ax[k], acc);
#pragma unroll
    for (int k = 0; k < KSH; ++k)
      acc = MFMA16(*(const f16x8*)(wrow + 32 * (KSX + k)), ah[k], acc);
    const float4 bb = *(const float4*)&bg[n0 + 16 * i + 4 * lg];
    float gi = sigm(acc[0] + bb.x);
    float gf = sigm(acc[1] + bb.y);
    float gg = ftanh(acc[2] + bb.z);
    float go = sigm(acc[3] + bb.w);
    int cu = cub + ((nc0 + 16 * i) >> 2) + lg;
    float cold = cS[l15][cu];
    float cnew = gf * cold + gi * gg;
    cS[l15][cu] = cnew;
    h16[l15][cu] = (f16)(go * ftanh(cnew));
    bufA[l15][cu] = (f16)cold;
    bufA[l15][256 + cu] = (f16)cnew;
  }
}

template <int ZX>
__global__ __launch_bounds__(512, 2) void fused_seq(MainArgs A, int t0, int cs,
                                                    int first, int last) {
  __shared__ f16  h16[16][264];
  __shared__ float cS[16][260];
  __shared__ float mS[16][260];
  __shared__ f16  bufA[16][808];    // cstar/attended (0:512) | m fp16 (512:768)
  __shared__ f16  hid16[16][264];
  __shared__ f16  ghid16[16][264];
  __shared__ float zf[16][516];

  const int tid = threadIdx.x;
  const int wid = tid >> 6, lane = tid & 63, l15 = lane & 15, lg = lane >> 4;
  const int r0 = blockIdx.x * 16;

  if (first) {
    for (int idx = tid; idx < 4096; idx += 512) {
      int r = idx >> 8, c = idx & 255, R = r0 + r;
      h16[r][c] = (f16)0.f;
      float cv = (c < 128) ? A.c_t[R * 128 + c]
                           : (c < 192 ? A.c_a[R * 64 + c - 128] : A.c_v[R * 64 + c - 192]);
      cS[r][c] = cv;
      mS[r][c] = A.mem0[R * 256 + c];
    }
  } else {
    for (int idx = tid; idx < 4096; idx += 512) {
      int r = idx >> 8, c = idx & 255;
      size_t g = (size_t)(r0 + r) * 256 + c;
      h16[r][c] = A.Hst[g];
      cS[r][c] = A.Cst[g];
      mS[r][c] = A.Mst[g];
    }
  }
  __syncthreads();

#pragma unroll 1
  for (int ts = 0; ts < cs; ++ts) {
    // ================= STAGE G: LSTM gates =================================
    if (ZX) {
      const f16* zxr = A.zx + ((size_t)ts * 4096 + r0 + l15) * 1024;
      f16x8 ah[4];
      if (wid < 4)      gload_zx<4>(h16, 0, l15, lg, ah);
      else if (wid < 6) gload_zx<2>(h16, 128, l15, lg, ah);
      else              gload_zx<2>(h16, 192, l15, lg, ah);
      __syncthreads();
      if (wid < 4)
        gmm_zxB<4, 448, 320>(A.Wg_t, A.bg, zxr, 128 * wid, 128 * wid, 0, ah, l15, lg, h16, cS, bufA);
      else if (wid < 6)
        gmm_zxB<2, 160, 96>(A.Wg_a, A.bg, zxr, 128 * (wid - 4), 512 + 128 * (wid - 4), 128, ah, l15, lg, h16, cS, bufA);
      else
        gmm_zxB<2, 448, 384>(A.Wg_v, A.bg, zxr, 128 * (wid - 6), 768 + 128 * (wid - 6), 192, ah, l15, lg, h16, cS, bufA);
    } else {
      const float* xrowf = A.x_p + ((size_t)(t0 + ts) * 4096 + r0 + l15) * 752;
      f16x8 ax[12], ah[4];
      if (wid < 4)      gate_load_full<10, 4, 300>(xrowf, 0, ax, ah, h16, l15, lg);
      else if (wid < 6) gate_load_full<3, 2, 81>(xrowf + 300, 128, ax, ah, h16, l15, lg);
      else              gate_load_full<12, 2, 371>(xrowf + 381, 192, ax, ah, h16, l15, lg);
      __syncthreads();
      if (wid < 4)
        gate_mm_full<10, 4, 448>(A.Wg_t, A.bg, 128 * wid, 128 * wid, 0, ax, ah, l15, lg, h16, cS, bufA);
      else if (wid < 6)
        gate_mm_full<3, 2, 160>(A.Wg_a, A.bg, 128 * (wid - 4), 512 + 128 * (wid - 4), 128, ax, ah, l15, lg, h16, cS, bufA);
      else
        gate_mm_full<12, 2, 448>(A.Wg_v, A.bg, 128 * (wid - 6), 768 + 128 * (wid - 6), 192, ax, ah, l15, lg, h16, cS, bufA);
    }
    __syncthreads();

    // ================= attn1 L1: hid = relu(cstar @ W^T + b) ===============
    {
      int n = 16 * wid;
      f32x4 acc = fc_tileB<16, 808>(bufA, 0, A.W_a1 + (size_t)(n + l15) * 512 + 8 * lg, l15, lg);
      float b = A.a1b1[n + l15];
#pragma unroll
      for (int q = 0; q < 4; ++q) hid16[lg * 4 + q][n + l15] = (f16)fmaxf(acc[q] + b, 0.f);
    }
    __syncthreads();

    // ================= attn1 L2: logits, 4 tiles/wave ======================
    {
#pragma unroll
      for (int i = 0; i < 4; ++i) {
        int n = 64 * wid + 16 * i + l15;
        f32x4 acc = fc_tileB<4, 264>(hid16, 0, A.W_a2 + (size_t)n * 128 + 8 * lg, l15, lg);
        float b = A.a1b2[n];
#pragma unroll
        for (int q = 0; q < 4; ++q) zf[lg * 4 + q][n] = acc[q] + b;
      }
    }
    __syncthreads();

    // ================= softmax * cstar (in place), m -> bufA[512:768] ======
    {
      int row = tid >> 5, c0 = tid & 31;
      float v[16]; float mx = -1e30f;
#pragma unroll
      for (int j = 0; j < 16; ++j) { v[j] = zf[row][c0 + 32 * j]; mx = fmaxf(mx, v[j]); }
#pragma unroll
      for (int m = 1; m < 32; m <<= 1) mx = fmaxf(mx, __shfl_xor(mx, m));
      float s = 0.f;
#pragma unroll
      for (int j = 0; j < 16; ++j) { v[j] = __expf(v[j] - mx); s += v[j]; }
#pragma unroll
      for (int m = 1; m < 32; m <<= 1) s += __shfl_xor(s, m);
      float inv = __builtin_amdgcn_rcpf(s);
#pragma unroll
      for (int j = 0; j < 16; ++j) {
        int c = c0 + 32 * j;
        bufA[row][c] = (f16)(v[j] * inv * (float)bufA[row][c]);
      }
      for (int idx = tid; idx < 4096; idx += 512) {
        int r = idx >> 8, c = idx & 255;
        bufA[r][512 + c] = (f16)mS[r][c];
      }
    }
    __syncthreads();

    // ====== stage 6 (balanced): every wave 2 ghid tiles + 1 attn2L1 tile ===
    {
#pragma unroll 1
      for (int i = 0; i < 2; ++i) {
        int nn = 16 * (2 * wid + i) + l15;
        f32x4 acc = fc_tileB<24, 808>(bufA, 0, A.W_g1 + (size_t)nn * 768 + 8 * lg, l15, lg);
        float b = (nn < 128) ? A.g1b1[nn] : A.g2b1[nn - 128];
#pragma unroll
        for (int q = 0; q < 4; ++q) ghid16[lg * 4 + q][nn] = (f16)fmaxf(acc[q] + b, 0.f);
      }
      {
        int n = 16 * wid;
        f32x4 acc = fc_tileB<16, 808>(bufA, 0, A.W_b1 + (size_t)(n + l15) * 512 + 8 * lg, l15, lg);
        float b = A.a2b1[n + l15];
#pragma unroll
        for (int q = 0; q < 4; ++q) hid16[lg * 4 + q][n + l15] = (f16)fmaxf(acc[q] + b, 0.f);
      }
    }
    __syncthreads();

    // ====== stage 7: attn2 L2 + g1/g2 second layers + m-update (batched) ===
    {
#pragma unroll 1
      for (int i = 0; i < 2; ++i) {
        int n = 32 * wid + 16 * i + l15;
        const f16* wbp = A.W_b2 + (size_t)n * 128 + 8 * lg;
        const f16* w1p = A.W_g2 + (size_t)n * 128 + 8 * lg;
        const f16* w2p = A.W_g2 + (size_t)(256 + n) * 128 + 8 * lg;
        f16x8 wB[4], w1[4], w2[4];
#pragma unroll
        for (int k = 0; k < 4; ++k) {
          wB[k] = *(const f16x8*)(wbp + 32 * k);
          w1[k] = *(const f16x8*)(w1p + 32 * k);
          w2[k] = *(const f16x8*)(w2p + 32 * k);
        }
        f32x4 acB = {0.f, 0.f, 0.f, 0.f};
        f32x4 ac1 = {0.f, 0.f, 0.f, 0.f};
        f32x4 ac2 = {0.f, 0.f, 0.f, 0.f};
#pragma unroll
        for (int k = 0; k < 4; ++k) {
          f16x8 ha = *(const f16x8*)(&hid16[l15][8 * lg + 32 * k]);
          f16x8 ga1 = *(const f16x8*)(&ghid16[l15][8 * lg + 32 * k]);
          f16x8 ga2 = *(const f16x8*)(&ghid16[l15][128 + 8 * lg + 32 * k]);
          acB = MFMA16(ha, wB[k], acB);
          ac1 = MFMA16(ga1, w1[k], ac1);
          ac2 = MFMA16(ga2, w2[k], ac2);
        }
        float bB = A.a2b2[n], b1 = A.g1b2[n], b2 = A.g2b2[n];
#pragma unroll
        for (int q = 0; q < 4; ++q) {
          int row = lg * 4 + q;
          float ch = ftanh(acB[q] + bB);
          float g1 = sigm(ac1[q] + b1);
          float g2 = sigm(ac2[q] + b2);
          mS[row][n] = g1 * mS[row][n] + g2 * ch;
        }
      }
    }
    __syncthreads();
  }

  if (last) {
    // ================= output head ========================================
    for (int idx = tid; idx < 4096; idx += 512) {
      int r = idx >> 8, c = idx & 255;
      bufA[r][c] = h16[r][c];
      bufA[r][256 + c] = (f16)mS[r][c];
    }
    __syncthreads();
    {
      int n = 16 * wid;
      f32x4 acc = fc_tileB<16, 808>(bufA, 0, A.W_o1 + (size_t)(n + l15) * 512 + 8 * lg, l15, lg);
      float b = A.ob1[n + l15];
#pragma unroll
      for (int q = 0; q < 4; ++q) hid16[lg * 4 + q][n + l15] = (f16)fmaxf(acc[q] + b, 0.f);
    }
    __syncthreads();
    {
      int row = tid >> 5, c0 = tid & 31;
      float s = 0.f;
#pragma unroll
      for (int j = 0; j < 4; ++j) { int k = c0 + 32 * j; s += (float)hid16[row][k] * A.oW2[k]; }
#pragma unroll
      for (int m = 1; m < 32; m <<= 1) s += __shfl_xor(s, m);
      if (c0 == 0) A.out[r0 + row] = s + A.ob2[0];
    }
  } else {
    for (int idx = tid; idx < 4096; idx += 512) {
      int r = idx >> 8, c = idx & 255;
      size_t g = (size_t)(r0 + r) * 256 + c;
      A.Hst[g] = h16[r][c];
      A.Cst[g] = cS[r][c];
      A.Mst[g] = mS[r][c];
    }
  }
}

extern "C" void kernel_launch(void* const* d_in, const int* in_sizes, int n_in,
                              void* d_out, int out_size, void* d_ws, size_t ws_size,
                              hipStream_t stream) {
  (void)in_sizes; (void)n_in; (void)out_size;
  char* w = (char*)d_ws;
  f16* Wg_t = (f16*)(w + 0);
  f16* Wg_a = (f16*)(w + 458752);
  f16* Wg_v = (f16*)(w + 540672);
  f16* W_a1 = (f16*)(w + 770048);
  f16* W_a2 = (f16*)(w + 901120);
  f16* W_b1 = (f16*)(w + 1032192);
  f16* W_b2 = (f16*)(w + 1163264);
  f16* W_g1 = (f16*)(w + 1228800);
  f16* W_g2 = (f16*)(w + 1622016);
  f16* W_o1 = (f16*)(w + 1753088);
  float* bg = (float*)(w + 1884160);
  f16* Hst = (f16*)(w + 1888256);
  float* Cst = (float*)(w + 3985408);
  float* Mst = (float*)(w + 8179712);
  f16* zx = (f16*)(w + 12374016);

  size_t avail = (ws_size > 12374016) ? ws_size - 12374016 : 0;
  const size_t per_step = (size_t)4096 * 1024 * 2;
  int cs = 0;
  const int divs[6] = {20, 10, 5, 4, 2, 1};
  for (int i = 0; i < 6; ++i)
    if ((size_t)divs[i] * per_step <= avail) { cs = divs[i]; break; }

  PackArgs pa;
  pa.t_Wih = (const float*)d_in[5];  pa.t_Whh = (const float*)d_in[6];  pa.t_b = (const float*)d_in[7];
  pa.a_Wih = (const float*)d_in[8];  pa.a_Whh = (const float*)d_in[9];  pa.a_b = (const float*)d_in[10];
  pa.v_Wih = (const float*)d_in[11]; pa.v_Whh = (const float*)d_in[12]; pa.v_b = (const float*)d_in[13];
  pa.aW1 = (const float*)d_in[14];  pa.aW2 = (const float*)d_in[16];
  pa.bW1 = (const float*)d_in[18];  pa.bW2 = (const float*)d_in[20];
  pa.g1W1 = (const float*)d_in[22]; pa.g2W1 = (const float*)d_in[26];
  pa.g1W2 = (const float*)d_in[24]; pa.g2W2 = (const float*)d_in[28];
  pa.oW1 = (const float*)d_in[30];
  pa.Wg_t = Wg_t; pa.Wg_a = Wg_a; pa.Wg_v = Wg_v; pa.W_a1 = W_a1; pa.W_a2 = W_a2;
  pa.W_b1 = W_b1; pa.W_b2 = W_b2; pa.W_g1 = W_g1; pa.W_g2 = W_g2; pa.W_o1 = W_o1;
  pa.bg = bg;
  pack_w<<<3684, 256, 0, stream>>>(pa);

  MainArgs ma;
  ma.x_p = (const float*)d_in[0];
  ma.c_t = (const float*)d_in[1]; ma.c_a = (const float*)d_in[2]; ma.c_v = (const float*)d_in[3];
  ma.mem0 = (const float*)d_in[4];
  ma.Wg_t = Wg_t; ma.Wg_a = Wg_a; ma.Wg_v = Wg_v; ma.W_a1 = W_a1; ma.W_a2 = W_a2;
  ma.W_b1 = W_b1; ma.W_b2 = W_b2; ma.W_g1 = W_g1; ma.W_g2 = W_g2; ma.W_o1 = W_o1;
  ma.bg = bg;
  ma.a1b1 = (const float*)d_in[15]; ma.a1b2 = (const float*)d_in[17];
  ma.a2b1 = (const float*)d_in[19]; ma.a2b2 = (const float*)d_in[21];
  ma.g1b1 = (const float*)d_in[23]; ma.g1b2 = (const float*)d_in[25];
  ma.g2b1 = (const float*)d_in[27]; ma.g2b2 = (const float*)d_in[29];
  ma.ob1 = (const float*)d_in[31]; ma.oW2 = (const float*)d_in[32]; ma.ob2 = (const float*)d_in[33];
  ma.Hst = Hst; ma.Cst = Cst; ma.Mst = Mst; ma.zx = zx;
  ma.out = (float*)d_out;

  if (cs > 0) {
    for (int t0 = 0; t0 < 20; t0 += cs) {
      ZxArgs za; za.x = (const float*)d_in[0];
      za.Wg_t = Wg_t; za.Wg_a = Wg_a; za.Wg_v = Wg_v; za.zx = zx; za.t0 = t0;
      gemm_zx<<<dim3(cs * 128), 512, 0, stream>>>(za);
      fused_seq<1><<<256, 512, 0, stream>>>(ma, t0, cs, t0 == 0 ? 1 : 0,
                                            (t0 + cs >= 20) ? 1 : 0);
    }
  } else {
    fused_seq<0><<<256, 512, 0, stream>>>(ma, 0, 20, 1, 1);
  }
}